// Round 3
// baseline (778.688 us; speedup 1.0000x reference)
//
#include <hip/hip_runtime.h>

#define N_SRC 16
#define T_DIM 64
#define GXD 256
#define GYD 256
#define GQD 256
#define HN 4
#define DN 8
#define TI 8               // outputs (i) per block
#define ROWS 12            // LDS rows per plane buffer (dest = 768 chunks = 3*256)
#define ROWSV 10           // rows actually consumed (span <= 10)
#define NB 3               // plane ring buffers (depth-2 pipeline)
#define NPLANES (2 * N_SRC)
#define CHPP 3             // global_load_lds issues per thread per plane (uniform)
#define USED_CHUNKS (ROWSV * 64)
#define PLANE_STRIDE ((size_t)T_DIM * GXD * GYD)
#define OUT_C_ELEMS (2 * T_DIM * GQD * GQD)

// d_ws layout (bytes) — 52224 total, same footprint as prior rounds:
#define WS_IY   0          // int   [N_SRC*GQD]  16384
#define WS_WY01 16384      // float2[N_SRC*GQD]  32768 (ends 49152)
#define WS_IX   49152      // int   [GQD]         1024
#define WS_WX0  50176      // float [GQD]
#define WS_WX1  51200      // float [GQD]

__device__ __forceinline__ float unitv(int i) {
    return (i == GQD - 1) ? 1.0f : (float)i * (1.0f / 255.0f);
}

// One block, 256 threads: attention/gaussian weights w[16] + packed y/x tables.
__global__ __launch_bounds__(256) void table_kernel(
    const float* __restrict__ xg, const float* __restrict__ yg,
    const float* __restrict__ params,
    const float* __restrict__ Wq_w, const float* __restrict__ Wq_b,
    const float* __restrict__ Wk_w, const float* __restrict__ Wk_b,
    const float* __restrict__ lyt_p, const float* __restrict__ ccut_p,
    const float* __restrict__ cnit_p,
    float* __restrict__ out_w, char* __restrict__ ws)
{
    __shared__ float xg_sm[GXD];
    __shared__ float ys_sm[N_SRC][GYD];
    __shared__ float w_sm[N_SRC];

    const int tid = threadIdx.x;
    const float lyt = *lyt_p;

    xg_sm[tid] = xg[tid];
    #pragma unroll
    for (int n = 0; n < N_SRC; ++n) {
        float s = lyt / params[n * 3 + 0];
        ys_sm[n][tid] = yg[n * GYD + tid] * s;
    }

    if (tid == 0) {
        const float ccut = *ccut_p, cnit = *cnit_p;
        float tgt[3];
        tgt[0] = (lyt - 30.0f) / 90.0f;
        tgt[1] = ccut / 0.0029f;
        tgt[2] = cnit / 0.0018f;
        float q[HN * DN];
        for (int hd = 0; hd < HN * DN; ++hd)
            q[hd] = tgt[0] * Wq_w[hd * 3 + 0] + tgt[1] * Wq_w[hd * 3 + 1] + tgt[2] * Wq_w[hd * 3 + 2] + Wq_b[hd];
        float p[N_SRC][3];
        float attn[N_SRC][HN];
        for (int n = 0; n < N_SRC; ++n) {
            p[n][0] = (params[n * 3 + 0] - 30.0f) / 90.0f;
            p[n][1] = params[n * 3 + 1] / 0.0029f;
            p[n][2] = params[n * 3 + 2] / 0.0018f;
            for (int h = 0; h < HN; ++h) {
                float acc = 0.0f;
                for (int d = 0; d < DN; ++d) {
                    int hd = h * DN + d;
                    float kv = p[n][0] * Wk_w[hd * 3 + 0] + p[n][1] * Wk_w[hd * 3 + 1] + p[n][2] * Wk_w[hd * 3 + 2] + Wk_b[hd];
                    acc += kv * q[hd];
                }
                attn[n][h] = acc / sqrtf(8.0f);
            }
        }
        float aw[N_SRC];
        for (int n = 0; n < N_SRC; ++n) aw[n] = 0.0f;
        for (int h = 0; h < HN; ++h) {
            float m = attn[0][h];
            for (int n = 1; n < N_SRC; ++n) m = fmaxf(m, attn[n][h]);
            float e[N_SRC], s = 0.0f;
            for (int n = 0; n < N_SRC; ++n) { e[n] = expf(attn[n][h] - m); s += e[n]; }
            for (int n = 0; n < N_SRC; ++n) aw[n] += e[n] / s;
        }
        for (int n = 0; n < N_SRC; ++n) aw[n] *= (1.0f / (float)HN);
        float sw[N_SRC], ss = 0.0f;
        for (int n = 0; n < N_SRC; ++n) {
            float d0 = (p[n][0] - tgt[0]) / 0.2f;
            float d1 = (p[n][1] - tgt[1]) / 0.2f;
            float d2 = (p[n][2] - tgt[2]) / 0.2f;
            sw[n] = expf(-0.5f * (d0 * d0 + d1 * d1 + d2 * d2));
            ss += sw[n];
        }
        float w[N_SRC], wsum = 0.0f;
        for (int n = 0; n < N_SRC; ++n) { w[n] = aw[n] * (sw[n] / ss); wsum += w[n]; }
        for (int n = 0; n < N_SRC; ++n) {
            float wf = w[n] / wsum;
            w_sm[n] = wf;
            out_w[n] = wf;
        }
    }
    __syncthreads();

    int*    iy_tab = (int*)   (ws + WS_IY);
    float2* wy_tab = (float2*)(ws + WS_WY01);
    int*    ix_tab = (int*)   (ws + WS_IX);
    float*  wx0_tab = (float*)(ws + WS_WX0);
    float*  wx1_tab = (float*)(ws + WS_WX1);

    const int j = tid;
    const float qy = unitv(j) * lyt;
    #pragma unroll
    for (int n = 0; n < N_SRC; ++n) {
        int lo = 0, hi = GYD;
        while (lo < hi) { int mid = (lo + hi) >> 1; if (ys_sm[n][mid] <= qy) lo = mid + 1; else hi = mid; }
        int idx = lo - 1;
        idx = idx < 0 ? 0 : (idx > GYD - 2 ? GYD - 2 : idx);
        float y0 = ys_sm[n][idx], y1 = ys_sm[n][idx + 1];
        float fy = (qy - y0) / (y1 - y0);
        float vy = (qy >= ys_sm[n][0] && qy <= ys_sm[n][GYD - 1]) ? 1.0f : 0.0f;
        float wn = w_sm[n] * vy;
        iy_tab[n * GQD + j] = idx;
        wy_tab[n * GQD + j] = make_float2(wn * (1.0f - fy), wn * fy);
    }

    const float Lx = xg_sm[GXD - 1];
    const float qx = unitv(tid) * Lx;
    int lo = 0, hi = GXD;
    while (lo < hi) { int mid = (lo + hi) >> 1; if (xg_sm[mid] <= qx) lo = mid + 1; else hi = mid; }
    int ixi = lo - 1;
    ixi = ixi < 0 ? 0 : (ixi > GXD - 2 ? GXD - 2 : ixi);
    const float x0 = xg_sm[ixi], x1 = xg_sm[ixi + 1];
    const float fx = (qx - x0) / (x1 - x0);
    const float vx = (qx >= xg_sm[0] && qx <= xg_sm[GXD - 1]) ? 1.0f : 0.0f;
    ix_tab [tid] = ixi;
    wx0_tab[tid] = vx * (1.0f - fx);
    wx1_tab[tid] = vx * fx;
}

__device__ __forceinline__ void gl_lds16(const float* g, float* l) {
    __builtin_amdgcn_global_load_lds(
        (const __attribute__((address_space(1))) void*)g,
        (__attribute__((address_space(3))) void*)l, 16, 0, 0);
}

// Depth-2 counted-vmcnt DMA pipeline, NB=3 ring, 36 KB LDS -> 4 blocks/CU.
// Counted stream per plane q:  [wait][barrier][fence][TLOAD? STAGE(q+2)][consume]
//   stage = 3 gl_lds / thread; table load (even planes) = 2 vmem instrs.
//   Even plane wait: out = {S(q):3, T:2, S(q+1):3}; S(q+1) strictly youngest ->
//     oldest-5 = {S(q),T} in any order -> vmcnt(3) retires S(q) exactly.
//   Odd plane wait:  out = {S(q):3, T:2, S(q+1):3}; S(q) strictly oldest ->
//     vmcnt(5) retires S(q) exactly. Last plane: vmcnt(0).
// Table-reg reads are compiler-guarded (its own loads), so correctness of the
// hand counts only ever covers the compiler-invisible global_load_lds data.
__global__ __launch_bounds__(256, 4) void fused_kernel(
    const float* __restrict__ c1, const float* __restrict__ c2,
    const float* __restrict__ ccut_p, const float* __restrict__ cnit_p,
    const char* __restrict__ ws, float* __restrict__ out)
{
    __shared__ float buf[NB][ROWS * GYD];   // 3 x 12 KB = 36 KB

    const int tid = threadIdx.x;
    const int j = tid;
    const int i0 = blockIdx.x * TI;
    const int t = blockIdx.y;

    const int*    iy_tab = (const int*)   (ws + WS_IY);
    const float2* wy_tab = (const float2*)(ws + WS_WY01);
    const int*    ix_tab = (const int*)   (ws + WS_IX);
    const float*  wx0_tab = (const float*)(ws + WS_WX0);
    const float*  wx1_tab = (const float*)(ws + WS_WX1);

    // x-side geometry (block-uniform -> SGPRs). ixi[i] in {i-1,i} =>
    // local row r0r[ii] = ii + d, d in {-1,0,1}; d==-1 impossible at ii==0.
    const int x0r = ix_tab[i0];
    int   dsel[TI];
    float wx0r[TI], wx1r[TI];
    #pragma unroll
    for (int ii = 0; ii < TI; ++ii) {
        int d = ix_tab[i0 + ii] - x0r - ii;
        dsel[ii] = d < -1 ? -1 : (d > 1 ? 1 : d);
        wx0r[ii] = wx0_tab[i0 + ii];
        wx1r[ii] = wx1_tab[i0 + ii];
    }

    // Per-thread staging geometry (identical for every plane).
    size_t soff[CHPP];
    int    ldst[CHPP];
    #pragma unroll
    for (int k = 0; k < CHPP; ++k) {
        int c  = tid + k * 256;
        int cc = c < USED_CHUNKS ? c : USED_CHUNKS - 1;
        int grow = x0r + (cc >> 6);
        grow = grow > GXD - 1 ? GXD - 1 : grow;
        soff[k] = (size_t)grow * GYD + ((cc & 63) << 2);
        ldst[k] = c << 2;
    }

    const size_t pbase = (size_t)t * (GXD * GYD);

    float acc1[TI], acc2[TI];
    #pragma unroll
    for (int ii = 0; ii < TI; ++ii) { acc1[ii] = 0.0f; acc2[ii] = 0.0f; }

    // cur/next packed table registers (replaces the 48-reg table file)
    int    tc_iy, tn_iy;
    float2 tc_wy, tn_wy;

#define FENCE asm volatile("" ::: "memory")

#define TLOAD(n) do {                                                          \
    tn_iy = iy_tab[(n) * GQD + j];        /* 1x global_load_dword   */         \
    tn_wy = wy_tab[(n) * GQD + j];        /* 1x global_load_dwordx2 */         \
} while (0)

#define STAGE(q) do {                                                          \
    const float* _s = (((q) & 1) ? c2 : c1) + pbase                            \
                      + (size_t)((q) >> 1) * PLANE_STRIDE;                     \
    float* _l = &buf[(q) % NB][0];                                             \
    gl_lds16(_s + soff[0], _l + ldst[0]);                                      \
    gl_lds16(_s + soff[1], _l + ldst[1]);                                      \
    gl_lds16(_s + soff[2], _l + ldst[2]);                                      \
} while (0)

#define CONSUME(q, ACC) do {                                                   \
    const float* _B = &buf[(q) % NB][0];                                       \
    const int _iy = tc_iy;                                                     \
    const float _w0 = tc_wy.x, _w1 = tc_wy.y;                                  \
    float _rv[ROWSV];                                                          \
    _Pragma("unroll")                                                          \
    for (int _r = 0; _r < ROWSV; ++_r)                                         \
        _rv[_r] = _w0 * _B[_r * GYD + _iy] + _w1 * _B[_r * GYD + _iy + 1];     \
    _Pragma("unroll")                                                          \
    for (int _ii = 0; _ii < TI; ++_ii) {                                       \
        const int _im1 = _ii > 0 ? _ii - 1 : 0;                                \
        const int _ip2 = _ii + 2 < ROWSV ? _ii + 2 : ROWSV - 1;                \
        const int _d = dsel[_ii];                                              \
        float _lo = _d == 0 ? _rv[_ii]     : (_d < 0 ? _rv[_im1] : _rv[_ii+1]);\
        float _hi = _d == 0 ? _rv[_ii + 1] : (_d < 0 ? _rv[_ii]  : _rv[_ip2]); \
        ACC[_ii] += wx0r[_ii] * _lo + wx1r[_ii] * _hi;                         \
    }                                                                          \
} while (0)

#define WAITQ(q) do {                                                          \
    if ((q) == NPLANES - 1)  asm volatile("s_waitcnt vmcnt(0)" ::: "memory");  \
    else if ((q) & 1)        asm volatile("s_waitcnt vmcnt(5)" ::: "memory");  \
    else                     asm volatile("s_waitcnt vmcnt(3)" ::: "memory");  \
} while (0)

#define PLANE(q) do {                                                          \
    WAITQ(q);                                                                  \
    __builtin_amdgcn_s_barrier();                                              \
    FENCE;  /* pin STAGE/consume below the barrier (ring reuse safety) */      \
    if (((q) & 1) == 0) {                                                      \
        tc_iy = tn_iy; tc_wy = tn_wy;                                          \
        if ((((q) >> 1) + 1) < N_SRC) TLOAD(((q) >> 1) + 1);                   \
    }                                                                          \
    if ((q) + 2 < NPLANES) STAGE((q) + 2);                                     \
    if (((q) & 1) == 0) CONSUME((q), acc1); else CONSUME((q), acc2);           \
} while (0)

    // Prologue: T0, S0, S1 — issue order pinned by fences (count: 2+3+3 = 8).
    TLOAD(0); FENCE;
    STAGE(0); FENCE;
    STAGE(1); FENCE;

    PLANE(0);  PLANE(1);  PLANE(2);  PLANE(3);
    PLANE(4);  PLANE(5);  PLANE(6);  PLANE(7);
    PLANE(8);  PLANE(9);  PLANE(10); PLANE(11);
    PLANE(12); PLANE(13); PLANE(14); PLANE(15);
    PLANE(16); PLANE(17); PLANE(18); PLANE(19);
    PLANE(20); PLANE(21); PLANE(22); PLANE(23);
    PLANE(24); PLANE(25); PLANE(26); PLANE(27);
    PLANE(28); PLANE(29); PLANE(30); PLANE(31);

#undef PLANE
#undef WAITQ
#undef CONSUME
#undef STAGE
#undef TLOAD
#undef FENCE

    const float ccut = *ccut_p, cnit = *cnit_p;
    #pragma unroll
    for (int ii = 0; ii < TI; ++ii) {
        const int i = i0 + ii;
        float o1 = acc1[ii];
        float o2 = acc2[ii];
        if (j == 0)       o1 = ccut;   // c1[:, :, 0]  = c_cu_target
        if (j == GQD - 1) o2 = cnit;   // c2[:, :, -1] = c_ni_target
        __builtin_nontemporal_store(o1, &out[((size_t)t * GQD + i) * GQD + j]);
        __builtin_nontemporal_store(o2, &out[(((size_t)T_DIM + t) * GQD + i) * GQD + j]);
    }
}

extern "C" void kernel_launch(void* const* d_in, const int* in_sizes, int n_in,
                              void* d_out, int out_size, void* d_ws, size_t ws_size,
                              hipStream_t stream) {
    const float* c1     = (const float*)d_in[0];
    const float* c2     = (const float*)d_in[1];
    const float* xg     = (const float*)d_in[2];
    const float* yg     = (const float*)d_in[3];
    const float* params = (const float*)d_in[4];
    const float* Wq_w   = (const float*)d_in[5];
    const float* Wq_b   = (const float*)d_in[6];
    const float* Wk_w   = (const float*)d_in[7];
    const float* Wk_b   = (const float*)d_in[8];
    const float* lyt    = (const float*)d_in[9];
    const float* ccut   = (const float*)d_in[10];
    const float* cnit   = (const float*)d_in[11];
    float* out = (float*)d_out;
    float* out_w = out + OUT_C_ELEMS;  // w[16] tail of the tuple output
    char* ws = (char*)d_ws;

    table_kernel<<<1, 256, 0, stream>>>(xg, yg, params, Wq_w, Wq_b, Wk_w, Wk_b,
                                        lyt, ccut, cnit, out_w, ws);
    dim3 grid(GQD / TI, T_DIM);
    fused_kernel<<<grid, 256, 0, stream>>>(c1, c2, ccut, cnit, ws, out);
}

// Round 4
// 583.596 us; speedup vs baseline: 1.3343x; 1.3343x over previous
//
#include <hip/hip_runtime.h>

#define N_SRC 16
#define T_DIM 64
#define GXD 256
#define GYD 256
#define GQD 256
#define HN 4
#define DN 8
#define TI 8               // outputs (i) per block
#define ROWS 12            // LDS rows per plane buffer (dest = 768 chunks = 3*256)
#define ROWSV 10           // rows actually consumed (span <= 10)
#define NB 3               // plane ring buffers (depth-2 pipeline)
#define NPLANES (2 * N_SRC)
#define CHPP 3             // global_load_lds issues per thread per plane (uniform)
#define USED_CHUNKS (ROWSV * 64)
#define PLANE_STRIDE ((size_t)T_DIM * GXD * GYD)
#define OUT_C_ELEMS (2 * T_DIM * GQD * GQD)

// d_ws layout (bytes):
#define WS_IY   0          // int   [N_SRC*GQD]  16384
#define WS_WY01 16384      // float2[N_SRC*GQD]  32768 (ends 49152)
#define WS_IX   49152      // int   [GQD]
#define WS_WX0  50176      // float [GQD]
#define WS_WX1  51200      // float [GQD]

__device__ __forceinline__ float unitv(int i) {
    return (i == GQD - 1) ? 1.0f : (float)i * (1.0f / 255.0f);
}

// One block, 256 threads: attention/gaussian weights w[16] + packed y/x tables.
__global__ __launch_bounds__(256) void table_kernel(
    const float* __restrict__ xg, const float* __restrict__ yg,
    const float* __restrict__ params,
    const float* __restrict__ Wq_w, const float* __restrict__ Wq_b,
    const float* __restrict__ Wk_w, const float* __restrict__ Wk_b,
    const float* __restrict__ lyt_p, const float* __restrict__ ccut_p,
    const float* __restrict__ cnit_p,
    float* __restrict__ out_w, char* __restrict__ ws)
{
    __shared__ float xg_sm[GXD];
    __shared__ float ys_sm[N_SRC][GYD];
    __shared__ float w_sm[N_SRC];

    const int tid = threadIdx.x;
    const float lyt = *lyt_p;

    xg_sm[tid] = xg[tid];
    #pragma unroll
    for (int n = 0; n < N_SRC; ++n) {
        float s = lyt / params[n * 3 + 0];
        ys_sm[n][tid] = yg[n * GYD + tid] * s;
    }

    if (tid == 0) {
        const float ccut = *ccut_p, cnit = *cnit_p;
        float tgt[3];
        tgt[0] = (lyt - 30.0f) / 90.0f;
        tgt[1] = ccut / 0.0029f;
        tgt[2] = cnit / 0.0018f;
        float q[HN * DN];
        for (int hd = 0; hd < HN * DN; ++hd)
            q[hd] = tgt[0] * Wq_w[hd * 3 + 0] + tgt[1] * Wq_w[hd * 3 + 1] + tgt[2] * Wq_w[hd * 3 + 2] + Wq_b[hd];
        float p[N_SRC][3];
        float attn[N_SRC][HN];
        for (int n = 0; n < N_SRC; ++n) {
            p[n][0] = (params[n * 3 + 0] - 30.0f) / 90.0f;
            p[n][1] = params[n * 3 + 1] / 0.0029f;
            p[n][2] = params[n * 3 + 2] / 0.0018f;
            for (int h = 0; h < HN; ++h) {
                float acc = 0.0f;
                for (int d = 0; d < DN; ++d) {
                    int hd = h * DN + d;
                    float kv = p[n][0] * Wk_w[hd * 3 + 0] + p[n][1] * Wk_w[hd * 3 + 1] + p[n][2] * Wk_w[hd * 3 + 2] + Wk_b[hd];
                    acc += kv * q[hd];
                }
                attn[n][h] = acc / sqrtf(8.0f);
            }
        }
        float aw[N_SRC];
        for (int n = 0; n < N_SRC; ++n) aw[n] = 0.0f;
        for (int h = 0; h < HN; ++h) {
            float m = attn[0][h];
            for (int n = 1; n < N_SRC; ++n) m = fmaxf(m, attn[n][h]);
            float e[N_SRC], s = 0.0f;
            for (int n = 0; n < N_SRC; ++n) { e[n] = expf(attn[n][h] - m); s += e[n]; }
            for (int n = 0; n < N_SRC; ++n) aw[n] += e[n] / s;
        }
        for (int n = 0; n < N_SRC; ++n) aw[n] *= (1.0f / (float)HN);
        float sw[N_SRC], ss = 0.0f;
        for (int n = 0; n < N_SRC; ++n) {
            float d0 = (p[n][0] - tgt[0]) / 0.2f;
            float d1 = (p[n][1] - tgt[1]) / 0.2f;
            float d2 = (p[n][2] - tgt[2]) / 0.2f;
            sw[n] = expf(-0.5f * (d0 * d0 + d1 * d1 + d2 * d2));
            ss += sw[n];
        }
        float w[N_SRC], wsum = 0.0f;
        for (int n = 0; n < N_SRC; ++n) { w[n] = aw[n] * (sw[n] / ss); wsum += w[n]; }
        for (int n = 0; n < N_SRC; ++n) {
            float wf = w[n] / wsum;
            w_sm[n] = wf;
            out_w[n] = wf;
        }
    }
    __syncthreads();

    int*    iy_tab = (int*)   (ws + WS_IY);
    float2* wy_tab = (float2*)(ws + WS_WY01);
    int*    ix_tab = (int*)   (ws + WS_IX);
    float*  wx0_tab = (float*)(ws + WS_WX0);
    float*  wx1_tab = (float*)(ws + WS_WX1);

    const int j = tid;
    const float qy = unitv(j) * lyt;
    #pragma unroll
    for (int n = 0; n < N_SRC; ++n) {
        int lo = 0, hi = GYD;
        while (lo < hi) { int mid = (lo + hi) >> 1; if (ys_sm[n][mid] <= qy) lo = mid + 1; else hi = mid; }
        int idx = lo - 1;
        idx = idx < 0 ? 0 : (idx > GYD - 2 ? GYD - 2 : idx);
        float y0 = ys_sm[n][idx], y1 = ys_sm[n][idx + 1];
        float fy = (qy - y0) / (y1 - y0);
        float vy = (qy >= ys_sm[n][0] && qy <= ys_sm[n][GYD - 1]) ? 1.0f : 0.0f;
        float wn = w_sm[n] * vy;
        iy_tab[n * GQD + j] = idx;
        wy_tab[n * GQD + j] = make_float2(wn * (1.0f - fy), wn * fy);
    }

    const float Lx = xg_sm[GXD - 1];
    const float qx = unitv(tid) * Lx;
    int lo = 0, hi = GXD;
    while (lo < hi) { int mid = (lo + hi) >> 1; if (xg_sm[mid] <= qx) lo = mid + 1; else hi = mid; }
    int ixi = lo - 1;
    ixi = ixi < 0 ? 0 : (ixi > GXD - 2 ? GXD - 2 : ixi);
    const float x0 = xg_sm[ixi], x1 = xg_sm[ixi + 1];
    const float fx = (qx - x0) / (x1 - x0);
    const float vx = (qx >= xg_sm[0] && qx <= xg_sm[GXD - 1]) ? 1.0f : 0.0f;
    ix_tab [tid] = ixi;
    wx0_tab[tid] = vx * (1.0f - fx);
    wx1_tab[tid] = vx * fx;
}

__device__ __forceinline__ void gl_lds16(const float* g, float* l) {
    __builtin_amdgcn_global_load_lds(
        (const __attribute__((address_space(1))) void*)g,
        (__attribute__((address_space(3))) void*)l, 16, 0, 0);
}

// Depth-2 counted-vmcnt DMA pipeline, NB=3 ring, 36 KB LDS -> 4 blocks/CU.
// Same counted stream as round 3 (waits verified robust to intra-segment
// reordering), but with a LEAN body: no rv[]/select temporaries, 32-bit
// staging offsets, direct per-ii LDS reads. Goal: fit the 128-VGPR budget of
// __launch_bounds__(256,4) with NO scratch spills (round 3's 790 MB of extra
// HBM traffic was spill thrash).
//   Even plane wait: vmcnt(3)  (retires S(q) + T)     Odd: vmcnt(5) (retires S(q))
//   Last plane: vmcnt(0).  lgkmcnt(0) added pre-barrier: closes the WAW window
//   between still-queued ds_reads of buf[q-1] and the post-barrier DMA overwrite.
__global__ __launch_bounds__(256, 4) void fused_kernel(
    const float* __restrict__ c1, const float* __restrict__ c2,
    const float* __restrict__ ccut_p, const float* __restrict__ cnit_p,
    const char* __restrict__ ws, float* __restrict__ out)
{
    __shared__ float buf[NB][ROWS * GYD];   // 3 x 12 KB = 36 KB

    const int tid = threadIdx.x;
    const int j = tid;
    const int i0 = blockIdx.x * TI;
    const int t = blockIdx.y;

    const int*    iy_tab = (const int*)   (ws + WS_IY);
    const float2* wy_tab = (const float2*)(ws + WS_WY01);
    const int*    ix_tab = (const int*)   (ws + WS_IX);
    const float*  wx0_tab = (const float*)(ws + WS_WX0);
    const float*  wx1_tab = (const float*)(ws + WS_WX1);

    // x-side geometry (block-uniform). ixi[i] in {i-1,i} => local base row for
    // output ii is rbo[ii]/GYD = ii + d, d in {-1,0,1}; d=-1 impossible at ii=0.
    const int x0r = ix_tab[i0];
    int   rbo [TI];          // precomputed LDS row offset (floats): (ii+d)*GYD
    float wx0r[TI], wx1r[TI];
    #pragma unroll
    for (int ii = 0; ii < TI; ++ii) {
        int d = ix_tab[i0 + ii] - x0r - ii;
        d = d < -1 ? -1 : (d > 1 ? 1 : d);
        rbo [ii] = (ii + d) * GYD;
        wx0r[ii] = wx0_tab[i0 + ii];
        wx1r[ii] = wx1_tab[i0 + ii];
    }

    // Per-thread staging geometry (identical for every plane), 32-bit offsets.
    int soff0, soff1, soff2;
    {
        int s[CHPP];
        #pragma unroll
        for (int k = 0; k < CHPP; ++k) {
            int c  = tid + k * 256;
            int cc = c < USED_CHUNKS ? c : USED_CHUNKS - 1;
            int grow = x0r + (cc >> 6);
            grow = grow > GXD - 1 ? GXD - 1 : grow;
            s[k] = grow * GYD + ((cc & 63) << 2);   // float offset, <= 65532
        }
        soff0 = s[0]; soff1 = s[1]; soff2 = s[2];
    }
    const int ldst0 = tid << 2;                     // dest float offset of chunk tid

    // Block-uniform plane base pointers (SGPR-resident).
    const size_t pbase = (size_t)t * (GXD * GYD);
    const float* c1p = c1 + pbase;
    const float* c2p = c2 + pbase;

    float acc1[TI], acc2[TI];
    #pragma unroll
    for (int ii = 0; ii < TI; ++ii) { acc1[ii] = 0.0f; acc2[ii] = 0.0f; }

    // cur/next packed table registers
    int    tc_iy, tn_iy;
    float2 tc_wy, tn_wy;

#define FENCE asm volatile("" ::: "memory")

#define TLOAD(n) do {                                                          \
    tn_iy = iy_tab[(n) * GQD + j];        /* 1x global_load_dword   */         \
    tn_wy = wy_tab[(n) * GQD + j];        /* 1x global_load_dwordx2 */         \
} while (0)

#define STAGE(q) do {                                                          \
    const float* _s = (((q) & 1) ? c2p : c1p)                                  \
                      + (size_t)((q) >> 1) * PLANE_STRIDE;                     \
    float* _l = &buf[(q) % NB][0] + ldst0;                                     \
    gl_lds16(_s + soff0, _l);                                                  \
    gl_lds16(_s + soff1, _l + 1024);                                           \
    gl_lds16(_s + soff2, _l + 2048);                                           \
} while (0)

#define CONSUME(q, ACC) do {                                                   \
    const float* _B = &buf[(q) % NB][0] + tc_iy;                               \
    const float _w0 = tc_wy.x, _w1 = tc_wy.y;                                  \
    _Pragma("unroll")                                                          \
    for (int _ii = 0; _ii < TI; ++_ii) {                                       \
        const float* _R = _B + rbo[_ii];                                       \
        float _lo = _w0 * _R[0]   + _w1 * _R[1];                               \
        float _hi = _w0 * _R[GYD] + _w1 * _R[GYD + 1];                         \
        ACC[_ii] += wx0r[_ii] * _lo + wx1r[_ii] * _hi;                         \
    }                                                                          \
} while (0)

#define WAITQ(q) do {                                                                       \
    if ((q) == NPLANES - 1)  asm volatile("s_waitcnt vmcnt(0) lgkmcnt(0)" ::: "memory");    \
    else if ((q) & 1)        asm volatile("s_waitcnt vmcnt(5) lgkmcnt(0)" ::: "memory");    \
    else                     asm volatile("s_waitcnt vmcnt(3) lgkmcnt(0)" ::: "memory");    \
} while (0)

#define PLANE(q) do {                                                          \
    WAITQ(q);                                                                  \
    __builtin_amdgcn_s_barrier();                                              \
    FENCE;  /* pin STAGE below the barrier (ring reuse safety) */              \
    if (((q) & 1) == 0) {                                                      \
        tc_iy = tn_iy; tc_wy = tn_wy;                                          \
        if ((((q) >> 1) + 1) < N_SRC) TLOAD(((q) >> 1) + 1);                   \
    }                                                                          \
    if ((q) + 2 < NPLANES) STAGE((q) + 2);                                     \
    if (((q) & 1) == 0) CONSUME((q), acc1); else CONSUME((q), acc2);           \
} while (0)

    // Prologue: T0, S0, S1 — issue order pinned by fences (vmcnt: 2+3+3 = 8).
    TLOAD(0); FENCE;
    STAGE(0); FENCE;
    STAGE(1); FENCE;

    PLANE(0);  PLANE(1);  PLANE(2);  PLANE(3);
    PLANE(4);  PLANE(5);  PLANE(6);  PLANE(7);
    PLANE(8);  PLANE(9);  PLANE(10); PLANE(11);
    PLANE(12); PLANE(13); PLANE(14); PLANE(15);
    PLANE(16); PLANE(17); PLANE(18); PLANE(19);
    PLANE(20); PLANE(21); PLANE(22); PLANE(23);
    PLANE(24); PLANE(25); PLANE(26); PLANE(27);
    PLANE(28); PLANE(29); PLANE(30); PLANE(31);

#undef PLANE
#undef WAITQ
#undef CONSUME
#undef STAGE
#undef TLOAD
#undef FENCE

    const float ccut = *ccut_p, cnit = *cnit_p;
    #pragma unroll
    for (int ii = 0; ii < TI; ++ii) {
        const int i = i0 + ii;
        float o1 = acc1[ii];
        float o2 = acc2[ii];
        if (j == 0)       o1 = ccut;   // c1[:, :, 0]  = c_cu_target
        if (j == GQD - 1) o2 = cnit;   // c2[:, :, -1] = c_ni_target
        __builtin_nontemporal_store(o1, &out[((size_t)t * GQD + i) * GQD + j]);
        __builtin_nontemporal_store(o2, &out[(((size_t)T_DIM + t) * GQD + i) * GQD + j]);
    }
}

extern "C" void kernel_launch(void* const* d_in, const int* in_sizes, int n_in,
                              void* d_out, int out_size, void* d_ws, size_t ws_size,
                              hipStream_t stream) {
    const float* c1     = (const float*)d_in[0];
    const float* c2     = (const float*)d_in[1];
    const float* xg     = (const float*)d_in[2];
    const float* yg     = (const float*)d_in[3];
    const float* params = (const float*)d_in[4];
    const float* Wq_w   = (const float*)d_in[5];
    const float* Wq_b   = (const float*)d_in[6];
    const float* Wk_w   = (const float*)d_in[7];
    const float* Wk_b   = (const float*)d_in[8];
    const float* lyt    = (const float*)d_in[9];
    const float* ccut   = (const float*)d_in[10];
    const float* cnit   = (const float*)d_in[11];
    float* out = (float*)d_out;
    float* out_w = out + OUT_C_ELEMS;  // w[16] tail of the tuple output
    char* ws = (char*)d_ws;

    table_kernel<<<1, 256, 0, stream>>>(xg, yg, params, Wq_w, Wq_b, Wk_w, Wk_b,
                                        lyt, ccut, cnit, out_w, ws);
    dim3 grid(GQD / TI, T_DIM);
    fused_kernel<<<grid, 256, 0, stream>>>(c1, c2, ccut, cnit, ws, out);
}